// Round 1
// 283.290 us; speedup vs baseline: 1.0229x; 1.0229x over previous
//
#include <hip/hip_runtime.h>

using bf16 = __bf16;
typedef bf16 bf16x4 __attribute__((ext_vector_type(4)));
typedef bf16 bf16x8 __attribute__((ext_vector_type(8)));
typedef float f32x4 __attribute__((ext_vector_type(4)));
typedef float f32x8 __attribute__((ext_vector_type(8)));

#define MFMA16(a, b, c) __builtin_amdgcn_mfma_f32_16x16x32_bf16(a, b, c, 0, 0, 0)

constexpr int Bb = 4, Tt = 2048, Dd = 1024, Hh = 16, Hd = 64;
constexpr int Mrows = Bb * Tt;                 // 8192
constexpr float CEXP = 0.18033688011112042f;   // (1/sqrt(64)) * log2(e), folded into Wq/bq

// async global->LDS, 16B per lane; LDS dst = wave-uniform base + lane*16 [m97/m104]
__device__ __forceinline__ void gload_lds16(const bf16* g, bf16* lds_base) {
  __builtin_amdgcn_global_load_lds((const __attribute__((address_space(1))) void*)g,
                                   (__attribute__((address_space(3))) void*)lds_base,
                                   16, 0, 0);
}

// ---------------------------------------------------------------- cast x -> bf16
__global__ void cast_f32_bf16_kernel(const float* __restrict__ in, bf16* __restrict__ out) {
  size_t i = ((size_t)blockIdx.x * 256 + threadIdx.x) * 8;
  f32x8 v = *(const f32x8*)(in + i);
  *(bf16x8*)(out + i) = __builtin_convertvector(v, bf16x8);
}

// ---- fused transpose+cast of all four weight matrices: W[k][n] f32 -> Wt[n][k] bf16
__global__ void transpose_cast_w4_kernel(const float* __restrict__ Wq, const float* __restrict__ Wk,
                                         const float* __restrict__ Wv, const float* __restrict__ Wo,
                                         bf16* __restrict__ Wt, bf16* __restrict__ Wot) {
  __shared__ alignas(16) float tile[64][68];
  const int tid = threadIdx.x;
  const int n0 = blockIdx.x * 64, k0 = blockIdx.y * 64, z = blockIdx.z;
  const float* W = (z == 0) ? Wq : (z == 1) ? Wk : (z == 2) ? Wv : Wo;
  bf16* dst = (z == 3) ? Wot : (Wt + (size_t)z * Dd * Dd);
  const float scale = (z == 0) ? CEXP : 1.0f;
#pragma unroll
  for (int it = 0; it < 4; ++it) {
    int chunk = tid + it * 256;
    int kr = chunk >> 4, c4 = chunk & 15;
    f32x4 v = *(const f32x4*)(W + (size_t)(k0 + kr) * Dd + n0 + c4 * 4);
    *(f32x4*)&tile[kr][c4 * 4] = v * scale;
  }
  __syncthreads();
#pragma unroll
  for (int it = 0; it < 2; ++it) {
    int chunk = tid + it * 256;
    int n = chunk & 63, k8 = chunk >> 6;
    bf16x8 o;
#pragma unroll
    for (int j = 0; j < 8; ++j) o[j] = (bf16)tile[k8 * 8 + j][n];
    *(bf16x8*)(dst + (size_t)(n0 + n) * Dd + k0 + k8 * 8) = o;
  }
}

// ---------------------------------------------------------------- pack qkv bias
__global__ void pack_bias_kernel(const float* __restrict__ bq, const float* __restrict__ bk,
                                 const float* __restrict__ bv, float* __restrict__ outb) {
  int i = blockIdx.x * 256 + threadIdx.x;
  float v = (i < 1024) ? bq[i] * CEXP : (i < 2048 ? bk[i - 1024] : bv[i - 2048]);
  outb[i] = v;
}

// --------- QKV GEMM, 256x256 tile / 512 threads / 8 waves (2M x 4N), BK=32.
// T3/T4: 4-slot LDS ring, stage tile t+3 during tile t (dest slot = the one tile t-1
// just vacated -> race-free), raw s_barrier + counted vmcnt(8) (2 tiles in flight),
// drained 8->4->0 only over the last 3 tiles. T2: XOR swizzle with linear
// global_load_lds dest via inverse-swizzled GLOBAL source (rule #21): 128B virtual
// rows (2 rows x 64B), chunk pos p = ((row&1)*4 + c16) ^ (vrow&7); frag reads are
// conflict-free (2-way max). T5: setprio(1) around each 16-MFMA cluster.
// Fused epilogue unchanged: Q/K -> QK[8192][2048], V -> Vt[b][h][d][t].
constexpr int QBM = 256, QBN = 256, QBK = 32, QNT = Dd / QBK;  // 32 K-tiles

#define VMW(n) asm volatile("s_waitcnt vmcnt(" #n ")" ::: "memory")

__global__ __launch_bounds__(512, 2)
void gemm_qkv_kernel(const bf16* __restrict__ A, const bf16* __restrict__ Bt,
                     const float* __restrict__ bias, bf16* __restrict__ QK,
                     bf16* __restrict__ Vt) {
  constexpr int KD = Dd;
  __shared__ alignas(16) bf16 As[4][QBM * QBK];   // 4 x 16 KiB
  __shared__ alignas(16) bf16 Bs[4][QBN * QBK];   // 4 x 16 KiB  (128 KiB total)
  const int tid = threadIdx.x;
  const int lane = tid & 63, wave = tid >> 6;
  const int col = lane & 15, quad = lane >> 4;
  const int wr = wave >> 2, wc = wave & 3;        // wave tile: 128 x 64
  const size_t m0 = (size_t)blockIdx.x * QBM, n0 = (size_t)blockIdx.y * QBN;

  // staging source pre-swizzle: lane l writes LDS vrow (g*8 + l>>3), pos (l&7);
  // it must FETCH logical (row, chunk) with u = (l&7)^(l>>3):
  const int u = (lane & 7) ^ (lane >> 3);
  const int srow = 2 * (lane >> 3) + (u >> 2);    // row within 16-row group
  const int scol = (u & 3) * 8;                   // element col within 32
  const bf16* Abase = A + (m0 + srow) * (size_t)KD + scol;
  const bf16* Bbase = Bt + (n0 + srow) * (size_t)KD + scol;

  // swizzled fragment read base: row R -> vrow R>>1, pos ((R&1)*4 | quad) ^ (vrow&7);
  // (vrow&7) == col>>1 for all i/j since frag rows step by 16.
  const int pswz = (((col & 1) << 2) | quad) ^ (col >> 1);
  const int afb = wr * 4096 + (col >> 1) * 64 + pswz * 8;  // + i*512
  const int bfb = wc * 2048 + (col >> 1) * 64 + pswz * 8;  // + j*512

  f32x4 acc[8][4];
#pragma unroll
  for (int i = 0; i < 8; ++i)
#pragma unroll
    for (int j = 0; j < 4; ++j)
#pragma unroll
      for (int r = 0; r < 4; ++r) acc[i][j][r] = 0.f;

#define QSTAGE_A(t, sl) do { \
    gload_lds16(Abase + (size_t)(t) * QBK + (size_t)(2 * wave + 0) * 16 * KD, &As[sl][(2 * wave + 0) * 512]); \
    gload_lds16(Abase + (size_t)(t) * QBK + (size_t)(2 * wave + 1) * 16 * KD, &As[sl][(2 * wave + 1) * 512]); \
  } while (0)
#define QSTAGE_B(t, sl) do { \
    gload_lds16(Bbase + (size_t)(t) * QBK + (size_t)(2 * wave + 0) * 16 * KD, &Bs[sl][(2 * wave + 0) * 512]); \
    gload_lds16(Bbase + (size_t)(t) * QBK + (size_t)(2 * wave + 1) * 16 * KD, &Bs[sl][(2 * wave + 1) * 512]); \
  } while (0)

// one K-tile = 2 phases; phase = {ds_read frags, stage, barrier, lgkmcnt(0),
// setprio, 16 MFMA, setprio, [vmcnt], barrier}
#define QKV_TILE(sl, STAGE0, STAGE1, VM) do { \
    bf16x8 af[4], bfv[4]; \
    _Pragma("unroll") for (int j = 0; j < 4; ++j) bfv[j] = *(const bf16x8*)&Bs[sl][bfb + j * 512]; \
    _Pragma("unroll") for (int i = 0; i < 4; ++i) af[i] = *(const bf16x8*)&As[sl][afb + i * 512]; \
    STAGE0; \
    __builtin_amdgcn_s_barrier(); \
    asm volatile("s_waitcnt lgkmcnt(0)" ::: "memory"); \
    __builtin_amdgcn_s_setprio(1); \
    _Pragma("unroll") for (int i = 0; i < 4; ++i) \
      _Pragma("unroll") for (int j = 0; j < 4; ++j) acc[i][j] = MFMA16(af[i], bfv[j], acc[i][j]); \
    __builtin_amdgcn_s_setprio(0); \
    __builtin_amdgcn_s_barrier(); \
    _Pragma("unroll") for (int i = 0; i < 4; ++i) af[i] = *(const bf16x8*)&As[sl][afb + (4 + i) * 512]; \
    STAGE1; \
    __builtin_amdgcn_s_barrier(); \
    asm volatile("s_waitcnt lgkmcnt(0)" ::: "memory"); \
    __builtin_amdgcn_s_setprio(1); \
    _Pragma("unroll") for (int i = 0; i < 4; ++i) \
      _Pragma("unroll") for (int j = 0; j < 4; ++j) acc[4 + i][j] = MFMA16(af[i], bfv[j], acc[4 + i][j]); \
    __builtin_amdgcn_s_setprio(0); \
    VM; \
    __builtin_amdgcn_s_barrier(); \
  } while (0)

  // prologue: tiles 0,1,2 staged; need tile 0 landed -> vmcnt(8) (tiles 1,2 in flight)
  QSTAGE_A(0, 0); QSTAGE_B(0, 0);
  QSTAGE_A(1, 1); QSTAGE_B(1, 1);
  QSTAGE_A(2, 2); QSTAGE_B(2, 2);
  VMW(8);
  __builtin_amdgcn_s_barrier();

#pragma unroll 1
  for (int t = 0; t < QNT - 4; t += 4) {          // tiles 0..27
    QKV_TILE(0, QSTAGE_A(t + 3, 3), QSTAGE_B(t + 3, 3), VMW(8));
    QKV_TILE(1, QSTAGE_A(t + 4, 0), QSTAGE_B(t + 4, 0), VMW(8));
    QKV_TILE(2, QSTAGE_A(t + 5, 1), QSTAGE_B(t + 5, 1), VMW(8));
    QKV_TILE(3, QSTAGE_A(t + 6, 2), QSTAGE_B(t + 6, 2), VMW(8));
  }
  QKV_TILE(0, QSTAGE_A(31, 3), QSTAGE_B(31, 3), VMW(8));  // tile 28
  QKV_TILE(1, (void)0, (void)0, VMW(4));                  // tile 29
  QKV_TILE(2, (void)0, (void)0, VMW(0));                  // tile 30
  QKV_TILE(3, (void)0, (void)0, (void)0);                 // tile 31

  if (n0 < 2048) {      // Q/K block -> compact [8192][2048] buffer
#pragma unroll
    for (int i = 0; i < 8; ++i)
#pragma unroll
      for (int j = 0; j < 4; ++j) {
        size_t row = m0 + wr * 128 + i * 16 + quad * 4;
        size_t c = n0 + wc * 64 + j * 16 + col;
        float bv = bias[c];
#pragma unroll
        for (int r = 0; r < 4; ++r) QK[(row + r) * 2048 + c] = (bf16)(acc[i][j][r] + bv);
      }
  } else {              // V block -> Vt[b][h][d][t], packed along t
#pragma unroll
    for (int i = 0; i < 8; ++i)
#pragma unroll
      for (int j = 0; j < 4; ++j) {
        size_t row = m0 + wr * 128 + i * 16 + quad * 4;
        int c = (int)(n0 + wc * 64 + j * 16 + col);
        float bv = bias[c];
        int dall = c - 2048, hh = dall >> 6, dd = dall & 63;
        int bi = (int)(row >> 11), trow = (int)(row & 2047);
        bf16x4 pk;
#pragma unroll
        for (int r = 0; r < 4; ++r) pk[r] = (bf16)(acc[i][j][r] + bv);
        *(bf16x4*)&Vt[((size_t)(bi * Hh + hh) * Hd + dd) * Tt + trow] = pk;
      }
  }
#undef QKV_TILE
#undef QSTAGE_A
#undef QSTAGE_B
}

// ------------------------- generic GEMM (out-projection): C = A @ Bt^T + bias
__global__ __launch_bounds__(256)
void gemm_bf16_kernel(const bf16* __restrict__ A, const bf16* __restrict__ Bt,
                      const float* __restrict__ bias, float* __restrict__ C,
                      int M, int N, int K) {
  __shared__ alignas(16) bf16 As[128 * 64];
  __shared__ alignas(16) bf16 Bs[128 * 64];
  const int tid = threadIdx.x;
  const int lane = tid & 63, wave = tid >> 6;
  const int col = lane & 15, quad = lane >> 4;
  const int wr = (wave >> 1) * 64, wc = (wave & 1) * 64;
  const size_t m0 = (size_t)blockIdx.x * 128, n0 = (size_t)blockIdx.y * 128;
  const int srow = lane >> 3, schunk = (lane & 7) * 8;

  f32x4 acc[4][4];
#pragma unroll
  for (int i = 0; i < 4; ++i)
#pragma unroll
    for (int j = 0; j < 4; ++j)
#pragma unroll
      for (int r = 0; r < 4; ++r) acc[i][j][r] = 0.f;

  for (int k0 = 0; k0 < K; k0 += 64) {
#pragma unroll
    for (int it = 0; it < 4; ++it) {
      int rbase = it * 32 + wave * 8;
      gload_lds16(A + (m0 + rbase + srow) * (size_t)K + k0 + schunk, &As[rbase * 64]);
      gload_lds16(Bt + (n0 + rbase + srow) * (size_t)K + k0 + schunk, &Bs[rbase * 64]);
    }
    __syncthreads();
#pragma unroll
    for (int kk = 0; kk < 2; ++kk) {
      bf16x8 af[4], bfr[4];
#pragma unroll
      for (int i = 0; i < 4; ++i) af[i] = *(const bf16x8*)&As[(wr + i * 16 + col) * 64 + kk * 32 + quad * 8];
#pragma unroll
      for (int j = 0; j < 4; ++j) bfr[j] = *(const bf16x8*)&Bs[(wc + j * 16 + col) * 64 + kk * 32 + quad * 8];
#pragma unroll
      for (int i = 0; i < 4; ++i)
#pragma unroll
        for (int j = 0; j < 4; ++j) acc[i][j] = MFMA16(af[i], bfr[j], acc[i][j]);
    }
    __syncthreads();
  }
#pragma unroll
  for (int i = 0; i < 4; ++i)
#pragma unroll
    for (int j = 0; j < 4; ++j) {
      size_t row = m0 + wr + i * 16 + quad * 4;
      size_t c = n0 + wc + j * 16 + col;
      float bv = bias[c];
#pragma unroll
      for (int r = 0; r < 4; ++r) C[(row + r) * (size_t)N + c] = acc[i][j][r] + bv;
    }
}

// ----------------------------------------------- flash attention, register-resident P
__global__ __launch_bounds__(256, 2)
void flash_attn_kernel(const bf16* __restrict__ qk, const bf16* __restrict__ vt,
                       const unsigned char* __restrict__ mask, bf16* __restrict__ ao) {
  __shared__ alignas(16) bf16 Ks[2][64 * 64];      // [key][slot^], xor-swizzled 16B slots
  __shared__ alignas(16) bf16 Vs[2][64 * 64];      // [d][slot^]
  __shared__ alignas(16) float lred[4][64];        // per-wave l transpose

  const int tid = threadIdx.x;
  const int wave = tid >> 6, lane = tid & 63;
  const int col = lane & 15, quad = lane >> 4;
  const int id = blockIdx.x;
  const int hb = id & 63, qi2 = id >> 6;           // id%8 -> XCD pinning per (b,h)
  const int h = hb & 15, b = hb >> 4;
  const int qbase0 = qi2 * 256 + wave * 64;

  const bf16* Qp = qk + (size_t)(b * Tt) * 2048 + h * Hd;
  const bf16* Kp = Qp + 1024;
  const bf16* Vp = vt + ((size_t)(b * Hh + h) * Hd) * Tt;
  const unsigned char* mp = mask + b * Tt;

  unsigned long long anym;
  {
    const unsigned long long* mq = (const unsigned long long*)mp;
    unsigned long long acc = 0;
#pragma unroll
    for (int j = 0; j < 4; ++j) acc |= mq[lane * 4 + j];
    anym = __ballot(acc != 0ull);
  }

  // Q fragments (pre-scaled by CEXP): free index = query
  bf16x8 qf[4][2];
#pragma unroll
  for (int t = 0; t < 4; ++t)
#pragma unroll
    for (int kk = 0; kk < 2; ++kk)
      qf[t][kk] = *(const bf16x8*)(Qp + (size_t)(qbase0 + t * 16 + col) * 2048 + kk * 32 + quad * 8);

  // staging map: row = lane, wave w stages 16B chunks {2w, 2w+1} of each row
  const bf16* Ksrc = Kp + (size_t)lane * 2048 + wave * 16;
  const bf16* Vsrc = Vp + (size_t)lane * Tt + wave * 16;
  const int ss1 = ((2 * wave) ^ (lane & 7)) * 8;
  const int ss2 = ((2 * wave + 1) ^ (lane & 7)) * 8;
  const int srowoff = lane * 64;

  {
    bf16x8 k0 = *(const bf16x8*)Ksrc, k1 = *(const bf16x8*)(Ksrc + 8);
    bf16x8 v0 = *(const bf16x8*)Vsrc, v1 = *(const bf16x8*)(Vsrc + 8);
    *(bf16x8*)&Ks[0][srowoff + ss1] = k0;  *(bf16x8*)&Ks[0][srowoff + ss2] = k1;
    *(bf16x8*)&Vs[0][srowoff + ss1] = v0;  *(bf16x8*)&Vs[0][srowoff + ss2] = v1;
  }
  __syncthreads();

  f32x4 oacc[4][4];
  float lsum[4];
#pragma unroll
  for (int t = 0; t < 4; ++t) {
    lsum[t] = 0.f;
#pragma unroll
    for (int n = 0; n < 4; ++n)
#pragma unroll
      for (int r = 0; r < 4; ++r) oacc[t][n][r] = 0.f;
  }
  const f32x4 zero4 = {0.f, 0.f, 0.f, 0.f};

  const int fslot0 = ((0 * 4 + quad) ^ (col & 7)) * 8;   // b128 frag slots (kf)
  const int fslot1 = ((1 * 4 + quad) ^ (col & 7)) * 8;
  const int voff = (quad & 1) * 4;

  for (int i = 0; i < 32; ++i) {
    const int cur = i & 1, nxt = cur ^ 1;
    const int kb = i * 64;

    bf16x8 nk0, nk1, nv0, nv1;
    if (i < 31) {
      const bf16* ks = Ksrc + (size_t)(kb + 64) * 2048;
      const bf16* vs = Vsrc + (kb + 64);
      nk0 = *(const bf16x8*)ks;  nk1 = *(const bf16x8*)(ks + 8);
      nv0 = *(const bf16x8*)vs;  nv1 = *(const bf16x8*)(vs + 8);
    }

    bf16x8 kf[4][2], vfs[4][2];
#pragma unroll
    for (int kt = 0; kt < 4; ++kt) {
      kf[kt][0] = *(const bf16x8*)&Ks[cur][(kt * 16 + col) * 64 + fslot0];
      kf[kt][1] = *(const bf16x8*)&Ks[cur][(kt * 16 + col) * 64 + fslot1];
    }
#pragma unroll
    for (int n = 0; n < 4; ++n) {
      const int row = (n * 16 + col) * 64;
      const int rx = col & 7;
#pragma unroll
      for (int kk = 0; kk < 2; ++kk) {
        bf16x4 lo = *(const bf16x4*)&Vs[cur][row + ((kk * 4 + 0 + (quad >> 1)) ^ rx) * 8 + voff];
        bf16x4 hi = *(const bf16x4*)&Vs[cur][row + ((kk * 4 + 2 + (quad >> 1)) ^ rx) * 8 + voff];
        vfs[n][kk] = __builtin_shufflevector(lo, hi, 0, 1, 2, 3, 4, 5, 6, 7);
      }
    }

#pragma unroll
    for (int t = 0; t < 4; ++t) {
      f32x4 s[4];
#pragma unroll
      for (int kt = 0; kt < 4; ++kt) s[kt] = MFMA16(kf[kt][0], qf[t][0], zero4);
#pragma unroll
      for (int kt = 0; kt < 4; ++kt) s[kt] = MFMA16(kf[kt][1], qf[t][1], s[kt]);

      if ((anym >> (2 * i)) & 3ull) {
#pragma unroll
        for (int kt = 0; kt < 4; ++kt)
#pragma unroll
          for (int r = 0; r < 4; ++r)
            if (mp[kb + kt * 16 + quad * 4 + r] != 0) s[kt][r] = -1e9f;
      }

      f32x4 e[4];
      float rs = 0.f;
#pragma unroll
      for (int kt = 0; kt < 4; ++kt)
#pragma unroll
        for (int r = 0; r < 4; ++r) {
          e[kt][r] = __builtin_amdgcn_exp2f(s[kt][r]);
          rs += e[kt][r];
        }
      bf16x4 c0 = __builtin_convertvector(e[0], bf16x4);
      bf16x4 c1 = __builtin_convertvector(e[1], bf16x4);
      bf16x4 c2 = __builtin_convertvector(e[2], bf16x4);
      bf16x4 c3 = __builtin_convertvector(e[3], bf16x4);
      bf16x8 pf0 = __builtin_shufflevector(c0, c1, 0, 1, 2, 3, 4, 5, 6, 7);
      bf16x8 pf1 = __builtin_shufflevector(c2, c3, 0, 1, 2, 3, 4, 5, 6, 7);
#pragma unroll
      for (int n = 0; n < 4; ++n) {
        oacc[t][n] = MFMA16(pf0, vfs[n][0], oacc[t][n]);
        oacc[t][n] = MFMA16(pf1, vfs[n][1], oacc[t][n]);
      }
      rs += __shfl_xor(rs, 16, 64);
      rs += __shfl_xor(rs, 32, 64);
      lsum[t] += rs;
    }

    if (i < 31) {
      *(bf16x8*)&Ks[nxt][srowoff + ss1] = nk0;  *(bf16x8*)&Ks[nxt][srowoff + ss2] = nk1;
      *(bf16x8*)&Vs[nxt][srowoff + ss1] = nv0;  *(bf16x8*)&Vs[nxt][srowoff + ss2] = nv1;
    }
    __syncthreads();
  }

  if (lane < 16) {
#pragma unroll
    for (int t = 0; t < 4; ++t) lred[wave][t * 16 + lane] = lsum[t];
  }
  __builtin_amdgcn_s_waitcnt(0xc07f);  // lgkmcnt(0), per-wave visibility
#pragma unroll
  for (int t = 0; t < 4; ++t) {
    f32x4 lv = *(const f32x4*)&lred[wave][t * 16 + quad * 4];
    f32x4 rl;
#pragma unroll
    for (int r = 0; r < 4; ++r) rl[r] = __builtin_amdgcn_rcpf(lv[r]);
#pragma unroll
    for (int n = 0; n < 4; ++n)
#pragma unroll
      for (int r = 0; r < 4; ++r) {
        size_t q = (size_t)b * Tt + qbase0 + t * 16 + quad * 4 + r;
        ao[q * Dd + h * Hd + n * 16 + col] = (bf16)(oacc[t][n][r] * rl[r]);
      }
  }
}

// --------------------------------------------------------------------- launcher
extern "C" void kernel_launch(void* const* d_in, const int* in_sizes, int n_in,
                              void* d_out, int out_size, void* d_ws, size_t ws_size,
                              hipStream_t stream) {
  const float* x = (const float*)d_in[0];
  const unsigned char* mask = (const unsigned char*)d_in[1];
  const float* Wq = (const float*)d_in[2];
  const float* bq = (const float*)d_in[3];
  const float* Wk = (const float*)d_in[4];
  const float* bk = (const float*)d_in[5];
  const float* Wv = (const float*)d_in[6];
  const float* bv = (const float*)d_in[7];
  const float* Wo = (const float*)d_in[8];
  const float* bo = (const float*)d_in[9];
  float* out = (float*)d_out;

  char* ws = (char*)d_ws;
  size_t off = 0;
  auto alloc = [&](size_t bytes) {
    char* p = ws + off;
    off += (bytes + 255) & ~(size_t)255;
    return p;
  };
  bf16* xb  = (bf16*)alloc((size_t)Mrows * Dd * 2);        // 16.8MB (reused as AO)
  bf16* Wt  = (bf16*)alloc((size_t)3 * Dd * Dd * 2);       // 6.3MB  packed [3072][1024]
  bf16* Wot = (bf16*)alloc((size_t)Dd * Dd * 2);           // 2.1MB
  bf16* QK  = (bf16*)alloc((size_t)Mrows * 2048 * 2);      // 33.6MB [8192][2048]
  bf16* Vt  = (bf16*)alloc((size_t)Bb * Hh * Hd * Tt * 2); // 16.8MB
  float* bqkv = (float*)alloc((size_t)3 * Dd * 4);

  cast_f32_bf16_kernel<<<Mrows * Dd / (256 * 8), 256, 0, stream>>>(x, xb);
  transpose_cast_w4_kernel<<<dim3(16, 16, 4), 256, 0, stream>>>(Wq, Wk, Wv, Wo, Wt, Wot);
  pack_bias_kernel<<<12, 256, 0, stream>>>(bq, bk, bv, bqkv);

  gemm_qkv_kernel<<<dim3(Mrows / QBM, 3 * Dd / QBN), 512, 0, stream>>>(
      xb, Wt, bqkv, QK, Vt);

  bf16* AO = xb;  // xb dead after QKV GEMM
  flash_attn_kernel<<<dim3(512), 256, 0, stream>>>(QK, Vt, mask, AO);
  gemm_bf16_kernel<<<dim3(Mrows / 128, Dd / 128), 256, 0, stream>>>(
      AO, Wot, bo, out, Mrows, Dd, Dd);
}